// Round 5
// baseline (169.469 us; speedup 1.0000x reference)
//
#include <hip/hip_runtime.h>

typedef unsigned long long u64;
typedef unsigned int u32;

#define D_FEAT 32
#define NPB 128            // nodes per bucket
#define BSHIFT 7           // log2(NPB)
#define NB_MAX 1024        // max bucket count supported by scan / LDS arrays
#define CAP 4096           // edges per bucket stageable in LDS (avg 2048 here)
#define GC_PAD 16          // pad cursors to 64 B to spread TCC channels
#define CBLK 512           // blocks for count
#define SBLK 2048          // blocks for scatter

// ---------- K1: per-block LDS histogram -> global bucket totals ----------
__global__ void count_kernel(const int* __restrict__ ei, int* __restrict__ btot,
                             int E, int NB, int epb) {
    __shared__ int hist[NB_MAX];
    for (int k = threadIdx.x; k < NB; k += blockDim.x) hist[k] = 0;
    __syncthreads();
    const int e0 = blockIdx.x * epb;
    const int e1 = min(E, e0 + epb);
    for (int e = e0 + threadIdx.x; e < e1; e += blockDim.x)
        atomicAdd(&hist[ei[e] >> BSHIFT], 1);
    __syncthreads();
    for (int k = threadIdx.x; k < NB; k += blockDim.x) {
        int v = hist[k];
        if (v) atomicAdd(&btot[k], v);
    }
}

// ---------- K2: exclusive scan of bucket totals; init global cursors ----------
__global__ void scan_init(const int* __restrict__ btot, int* __restrict__ bbase,
                          int* __restrict__ gcur, int NB) {
    __shared__ int lds[NB_MAX];
    const int t = threadIdx.x;
    const int v = (t < NB) ? btot[t] : 0;
    lds[t] = v;
    __syncthreads();
    for (int d = 1; d < NB_MAX; d <<= 1) {
        int tmp = (t >= d) ? lds[t - d] : 0;
        __syncthreads();
        lds[t] += tmp;
        __syncthreads();
    }
    if (t < NB) {
        int ex = lds[t] - v;
        bbase[t] = ex;
        gcur[t * GC_PAD] = ex;
    }
    if (t == NB - 1) bbase[NB] = lds[t];   // == E
}

// ---------- K3: scatter edges into bucket regions via global cursors ----------
__global__ void scatter_global(const int* __restrict__ ei, const float* __restrict__ attr,
                               int* __restrict__ gcur, u64* __restrict__ dstbuf, int E) {
    const int stride = gridDim.x * blockDim.x;
    for (int e = blockIdx.x * blockDim.x + threadIdx.x; e < E; e += stride) {
        const int s = ei[e];
        const u32 d = (u32)ei[E + e];
        const u32 a = __float_as_uint(attr[e]);
        const int pos = atomicAdd(&gcur[(s >> BSHIFT) * GC_PAD], 1);
        dstbuf[pos] = ((u64)a << 32) | (d | ((u32)(s & (NPB - 1)) << 20));
    }
}

// ---------- K4: per-bucket LDS counting sort A->B + node offsets ----------
__global__ void __launch_bounds__(256)
bucket_sort(const u64* __restrict__ srcbuf, u64* __restrict__ dstbuf,
            const int* __restrict__ bbase, int* __restrict__ node_off, int N, int NB) {
    __shared__ u64 stage[CAP];     // 32 KB
    __shared__ int hist[NPB];
    __shared__ int cur[NPB];
    const int k = blockIdx.x, t = threadIdx.x;
    const int start = bbase[k], end = bbase[k + 1];
    const int cnt = end - start;

    if (t < NPB) hist[t] = 0;
    __syncthreads();

    // stage + histogram
    for (int i = t; i < cnt; i += 256) {
        u64 p = srcbuf[start + i];
        if (i < CAP) stage[i] = p;
        atomicAdd(&hist[(int)(((u32)p >> 20) & (NPB - 1))], 1);
    }
    __syncthreads();

    // exclusive scan of 128 counters
    int orig = (t < NPB) ? hist[t] : 0;
    for (int d = 1; d < NPB; d <<= 1) {
        int tmp = (t >= d && t < NPB) ? hist[t - d] : 0;
        __syncthreads();
        if (t < NPB) hist[t] += tmp;
        __syncthreads();
    }
    if (t < NPB) {
        int excl = hist[t] - orig;
        cur[t] = excl;
        int node = (k << BSHIFT) + t;
        if (node < N) node_off[node] = start + excl;
    }
    if (k == NB - 1 && t == 0) node_off[N] = end;
    __syncthreads();

    // scatter into node order (ping-pong: reads of src are race-free)
    for (int i = t; i < cnt; i += 256) {
        u64 p = (i < CAP) ? stage[i] : srcbuf[start + i];
        int local = (int)(((u32)p >> 20) & (NPB - 1));
        int pos = atomicAdd(&cur[local], 1);
        dstbuf[start + pos] = p;
    }
}

// ---------- K5: node-parallel gather, 8 lanes/node, float4, 4-edge unroll ----------
__global__ void __launch_bounds__(256)
csr_gather(const u64* __restrict__ csr, const int* __restrict__ node_off,
           const float* __restrict__ x, float* __restrict__ out, int N) {
    const int gid = (blockIdx.x * 256 + threadIdx.x) >> 3;  // node
    const int l4 = (threadIdx.x & 7) << 2;                  // feature*4
    if (gid >= N) return;
    const int s = node_off[gid], e = node_off[gid + 1];

    float ax = 0.f, ay = 0.f, az = 0.f, aw = 0.f;
    int k = s;
    for (; k + 4 <= e; k += 4) {
        const u64 p0 = csr[k], p1 = csr[k + 1], p2 = csr[k + 2], p3 = csr[k + 3];
        const float4 v0 = *(const float4*)&x[(((size_t)((u32)p0 & 0xFFFFFu)) << 5) + l4];
        const float4 v1 = *(const float4*)&x[(((size_t)((u32)p1 & 0xFFFFFu)) << 5) + l4];
        const float4 v2 = *(const float4*)&x[(((size_t)((u32)p2 & 0xFFFFFu)) << 5) + l4];
        const float4 v3 = *(const float4*)&x[(((size_t)((u32)p3 & 0xFFFFFu)) << 5) + l4];
        const float a0 = __uint_as_float((u32)(p0 >> 32));
        const float a1 = __uint_as_float((u32)(p1 >> 32));
        const float a2 = __uint_as_float((u32)(p2 >> 32));
        const float a3 = __uint_as_float((u32)(p3 >> 32));
        ax = fmaf(a0, v0.x, ax); ay = fmaf(a0, v0.y, ay); az = fmaf(a0, v0.z, az); aw = fmaf(a0, v0.w, aw);
        ax = fmaf(a1, v1.x, ax); ay = fmaf(a1, v1.y, ay); az = fmaf(a1, v1.z, az); aw = fmaf(a1, v1.w, aw);
        ax = fmaf(a2, v2.x, ax); ay = fmaf(a2, v2.y, ay); az = fmaf(a2, v2.z, az); aw = fmaf(a2, v2.w, aw);
        ax = fmaf(a3, v3.x, ax); ay = fmaf(a3, v3.y, ay); az = fmaf(a3, v3.z, az); aw = fmaf(a3, v3.w, aw);
    }
    for (; k < e; ++k) {
        const u64 p = csr[k];
        const float4 v = *(const float4*)&x[(((size_t)((u32)p & 0xFFFFFu)) << 5) + l4];
        const float a = __uint_as_float((u32)(p >> 32));
        ax = fmaf(a, v.x, ax); ay = fmaf(a, v.y, ay); az = fmaf(a, v.z, az); aw = fmaf(a, v.w, aw);
    }
    float4 r; r.x = ax; r.y = ay; r.z = az; r.w = aw;
    *(float4*)&out[((size_t)gid << 5) + l4] = r;
}

// ---------- fallback (generality): direct atomic scatter ----------
__global__ void fallback_scatter(const int* __restrict__ ei, const float* __restrict__ attr,
                                 const float* __restrict__ x, float* __restrict__ out, int E) {
    const long long total = (long long)E * D_FEAT;
    const long long stride = (long long)gridDim.x * blockDim.x;
    for (long long i = (long long)blockIdx.x * blockDim.x + threadIdx.x; i < total; i += stride) {
        const int e = (int)(i >> 5);
        const int d = (int)(i & 31);
        atomicAdd(&out[((long long)ei[e] << 5) + d],
                  attr[e] * x[((long long)ei[E + e] << 5) + d]);
    }
}

extern "C" void kernel_launch(void* const* d_in, const int* in_sizes, int n_in,
                              void* d_out, int out_size, void* d_ws, size_t ws_size,
                              hipStream_t stream) {
    const int* edge_index = (const int*)d_in[0];    // [2, E] int32
    const float* edge_attr = (const float*)d_in[1]; // [E] f32
    const float* x = (const float*)d_in[2];         // [N, 32] f32
    float* out = (float*)d_out;                     // [N, 32] f32

    const int E = in_sizes[1];
    const int N = in_sizes[2] / D_FEAT;
    const int NB = (N + NPB - 1) >> BSHIFT;

    // Workspace layout (256-B aligned sections)
    char* ws = (char*)d_ws;
    int* btot = (int*)ws;                                              // NB
    size_t o1 = (((size_t)NB * 4) + 255) & ~(size_t)255;
    int* bbase = (int*)(ws + o1);                                      // NB+1
    size_t o2 = (o1 + ((size_t)(NB + 1) * 4) + 255) & ~(size_t)255;
    int* gcur = (int*)(ws + o2);                                       // NB*GC_PAD
    size_t o3 = (o2 + ((size_t)NB * GC_PAD * 4) + 255) & ~(size_t)255;
    int* node_off = (int*)(ws + o3);                                   // N+1
    size_t o4 = (o3 + ((size_t)(N + 1) * 4) + 255) & ~(size_t)255;
    u64* bufA = (u64*)(ws + o4);                                       // E
    size_t o5 = (o4 + ((size_t)E * 8) + 255) & ~(size_t)255;
    u64* bufB = (u64*)(ws + o5);                                       // E
    size_t need = o5 + (size_t)E * 8;

    if (NB > NB_MAX || N > (1 << 20) || need > ws_size) {
        hipMemsetAsync(d_out, 0, (size_t)out_size * sizeof(float), stream);
        long long total = (long long)E * D_FEAT;
        int grid = (int)((total + 255) / 256);
        if (grid > 65536) grid = 65536;
        fallback_scatter<<<grid, 256, 0, stream>>>(edge_index, edge_attr, x, out, E);
        return;
    }

    hipMemsetAsync(btot, 0, (size_t)NB * 4, stream);

    const int epb = (E + CBLK - 1) / CBLK;
    count_kernel<<<CBLK, 256, 0, stream>>>(edge_index, btot, E, NB, epb);
    scan_init<<<1, NB_MAX, 0, stream>>>(btot, bbase, gcur, NB);

    int sgrid = (E + 255) / 256;
    if (sgrid > SBLK) sgrid = SBLK;
    scatter_global<<<sgrid, 256, 0, stream>>>(edge_index, edge_attr, gcur, bufA, E);

    bucket_sort<<<NB, 256, 0, stream>>>(bufA, bufB, bbase, node_off, N, NB);

    const long long gthreads = (long long)N * 8;
    csr_gather<<<(int)((gthreads + 255) / 256), 256, 0, stream>>>(bufB, node_off, x, out, N);
}

// Round 6
// 84.477 us; speedup vs baseline: 2.0061x; 2.0061x over previous
//
#include <hip/hip_runtime.h>

typedef unsigned long long u64;
typedef unsigned int u32;

#define D_FEAT 32
#define NPB 128            // nodes per bucket
#define BSHIFT 7           // log2(NPB)
#define NB_MAX 1024        // max bucket count supported by scans / LDS arrays
#define NBLK 512           // edge-chunk blocks for count/scatter
#define ABLK 512           // threads per block for count/scatter
#define CAP 4096           // max edges per bucket stageable in LDS (avg 2048 here)

// ---------- A1: per-(block,bucket) histogram, no global atomics ----------
__global__ void __launch_bounds__(ABLK)
binA_count(const int* __restrict__ ei, int* __restrict__ cnt,
           int E, int NB, int epb) {
    __shared__ int hist[NB_MAX];
    for (int k = threadIdx.x; k < NB; k += blockDim.x) hist[k] = 0;
    __syncthreads();
    const int e0 = blockIdx.x * epb;
    const int e1 = min(E, e0 + epb);
    for (int e = e0 + threadIdx.x; e < e1; e += blockDim.x)
        atomicAdd(&hist[ei[e] >> BSHIFT], 1);
    __syncthreads();
    for (int k = threadIdx.x; k < NB; k += blockDim.x)
        cnt[(size_t)blockIdx.x * NB + k] = hist[k];
}

// ---------- S1: per bucket, exclusive scan over the NBLK block counts ----------
__global__ void __launch_bounds__(NBLK)
binS1(int* __restrict__ cnt, int* __restrict__ btot, int NB) {
    __shared__ int lds[NBLK];
    const int k = blockIdx.x, t = threadIdx.x;
    const int v = cnt[(size_t)t * NB + k];
    lds[t] = v;
    __syncthreads();
    for (int d = 1; d < NBLK; d <<= 1) {
        int tmp = (t >= d) ? lds[t - d] : 0;
        __syncthreads();
        lds[t] += tmp;
        __syncthreads();
    }
    cnt[(size_t)t * NB + k] = lds[t] - v;   // exclusive prefix within bucket
    if (t == NBLK - 1) btot[k] = lds[NBLK - 1];
}

// ---------- S2: exclusive scan of bucket totals (one block) ----------
__global__ void binS2(const int* __restrict__ btot, int* __restrict__ bbase, int NB) {
    __shared__ int lds[NB_MAX];
    const int t = threadIdx.x;
    const int v = (t < NB) ? btot[t] : 0;
    lds[t] = v;
    __syncthreads();
    for (int d = 1; d < NB_MAX; d <<= 1) {
        int tmp = (t >= d) ? lds[t - d] : 0;
        __syncthreads();
        lds[t] += tmp;
        __syncthreads();
    }
    if (t < NB) bbase[t] = lds[t] - v;
    if (t == NB - 1) bbase[NB] = lds[t];    // total = E
}

// ---------- A3: scatter edges into bucket-contiguous slots, LDS cursors ----------
__global__ void __launch_bounds__(ABLK)
binA_scatter(const int* __restrict__ ei, const float* __restrict__ attr,
             const int* __restrict__ cnt, const int* __restrict__ bbase,
             u64* __restrict__ dstbuf, int E, int NB, int epb) {
    __shared__ int cur[NB_MAX];
    for (int k = threadIdx.x; k < NB; k += blockDim.x)
        cur[k] = bbase[k] + cnt[(size_t)blockIdx.x * NB + k];
    __syncthreads();
    const int e0 = blockIdx.x * epb;
    const int e1 = min(E, e0 + epb);
    for (int e = e0 + threadIdx.x; e < e1; e += blockDim.x) {
        const int s = ei[e];
        const u32 d = (u32)ei[E + e];
        const u32 a = __float_as_uint(attr[e]);
        const int pos = atomicAdd(&cur[s >> BSHIFT], 1);
        const u32 lo = d | ((u32)(s & (NPB - 1)) << 20);  // dst(20b) | local_src(7b)
        dstbuf[pos] = ((u64)a << 32) | lo;
    }
}

// ---------- B: per-bucket LDS counting sort A->B + node offsets ----------
__global__ void __launch_bounds__(256)
bucket_sort(const u64* __restrict__ srcbuf, u64* __restrict__ dstbuf,
            const int* __restrict__ bbase, int* __restrict__ node_off, int N, int NB) {
    __shared__ u64 stage[CAP];     // 32 KB
    __shared__ int hist[NPB];
    __shared__ int cur[NPB];
    const int k = blockIdx.x, t = threadIdx.x;
    const int start = bbase[k], end = bbase[k + 1];
    const int cnt = end - start;

    if (t < NPB) hist[t] = 0;
    __syncthreads();

    // stage + histogram
    for (int i = t; i < cnt; i += 256) {
        u64 p = srcbuf[start + i];
        if (i < CAP) stage[i] = p;
        atomicAdd(&hist[(int)(((u32)p >> 20) & (NPB - 1))], 1);
    }
    __syncthreads();

    // exclusive scan of 128 counters
    int orig = (t < NPB) ? hist[t] : 0;
    for (int d = 1; d < NPB; d <<= 1) {
        int tmp = (t >= d && t < NPB) ? hist[t - d] : 0;
        __syncthreads();
        if (t < NPB) hist[t] += tmp;
        __syncthreads();
    }
    if (t < NPB) {
        int excl = hist[t] - orig;
        cur[t] = excl;
        int node = (k << BSHIFT) + t;
        if (node < N) node_off[node] = start + excl;
    }
    if (k == NB - 1 && t == 0) node_off[N] = end;
    __syncthreads();

    // scatter into node order (ping-pong: reads race-free)
    for (int i = t; i < cnt; i += 256) {
        u64 p = (i < CAP) ? stage[i] : srcbuf[start + i];
        int local = (int)(((u32)p >> 20) & (NPB - 1));
        int pos = atomicAdd(&cur[local], 1);
        dstbuf[start + pos] = p;
    }
}

// ---------- C: node-parallel gather, 8 lanes/node, float4, 4-edge unroll ----------
__global__ void __launch_bounds__(256)
csr_gather(const u64* __restrict__ csr, const int* __restrict__ node_off,
           const float* __restrict__ x, float* __restrict__ out, int N) {
    const int gid = (blockIdx.x * 256 + threadIdx.x) >> 3;  // node
    const int l4 = (threadIdx.x & 7) << 2;                  // feature*4
    if (gid >= N) return;
    const int s = node_off[gid], e = node_off[gid + 1];

    float ax = 0.f, ay = 0.f, az = 0.f, aw = 0.f;
    int k = s;
    for (; k + 4 <= e; k += 4) {
        const u64 p0 = csr[k], p1 = csr[k + 1], p2 = csr[k + 2], p3 = csr[k + 3];
        const float4 v0 = *(const float4*)&x[(((size_t)((u32)p0 & 0xFFFFFu)) << 5) + l4];
        const float4 v1 = *(const float4*)&x[(((size_t)((u32)p1 & 0xFFFFFu)) << 5) + l4];
        const float4 v2 = *(const float4*)&x[(((size_t)((u32)p2 & 0xFFFFFu)) << 5) + l4];
        const float4 v3 = *(const float4*)&x[(((size_t)((u32)p3 & 0xFFFFFu)) << 5) + l4];
        const float a0 = __uint_as_float((u32)(p0 >> 32));
        const float a1 = __uint_as_float((u32)(p1 >> 32));
        const float a2 = __uint_as_float((u32)(p2 >> 32));
        const float a3 = __uint_as_float((u32)(p3 >> 32));
        ax = fmaf(a0, v0.x, ax); ay = fmaf(a0, v0.y, ay); az = fmaf(a0, v0.z, az); aw = fmaf(a0, v0.w, aw);
        ax = fmaf(a1, v1.x, ax); ay = fmaf(a1, v1.y, ay); az = fmaf(a1, v1.z, az); aw = fmaf(a1, v1.w, aw);
        ax = fmaf(a2, v2.x, ax); ay = fmaf(a2, v2.y, ay); az = fmaf(a2, v2.z, az); aw = fmaf(a2, v2.w, aw);
        ax = fmaf(a3, v3.x, ax); ay = fmaf(a3, v3.y, ay); az = fmaf(a3, v3.z, az); aw = fmaf(a3, v3.w, aw);
    }
    for (; k < e; ++k) {
        const u64 p = csr[k];
        const float4 v = *(const float4*)&x[(((size_t)((u32)p & 0xFFFFFu)) << 5) + l4];
        const float a = __uint_as_float((u32)(p >> 32));
        ax = fmaf(a, v.x, ax); ay = fmaf(a, v.y, ay); az = fmaf(a, v.z, az); aw = fmaf(a, v.w, aw);
    }
    float4 r; r.x = ax; r.y = ay; r.z = az; r.w = aw;
    *(float4*)&out[((size_t)gid << 5) + l4] = r;
}

// ---------- fallback (generality): direct atomic scatter ----------
__global__ void fallback_scatter(const int* __restrict__ ei, const float* __restrict__ attr,
                                 const float* __restrict__ x, float* __restrict__ out, int E) {
    const long long total = (long long)E * D_FEAT;
    const long long stride = (long long)gridDim.x * blockDim.x;
    for (long long i = (long long)blockIdx.x * blockDim.x + threadIdx.x; i < total; i += stride) {
        const int e = (int)(i >> 5);
        const int d = (int)(i & 31);
        atomicAdd(&out[((long long)ei[e] << 5) + d],
                  attr[e] * x[((long long)ei[E + e] << 5) + d]);
    }
}

extern "C" void kernel_launch(void* const* d_in, const int* in_sizes, int n_in,
                              void* d_out, int out_size, void* d_ws, size_t ws_size,
                              hipStream_t stream) {
    const int* edge_index = (const int*)d_in[0];    // [2, E] int32
    const float* edge_attr = (const float*)d_in[1]; // [E] f32
    const float* x = (const float*)d_in[2];         // [N, 32] f32
    float* out = (float*)d_out;                     // [N, 32] f32

    const int E = in_sizes[1];
    const int N = in_sizes[2] / D_FEAT;
    const int NB = (N + NPB - 1) >> BSHIFT;

    // Workspace layout (256-B aligned sections)
    char* ws = (char*)d_ws;
    int* cnt = (int*)ws;                                               // NBLK*NB
    size_t o1 = (((size_t)NBLK * NB * 4) + 255) & ~(size_t)255;
    int* btot = (int*)(ws + o1);                                       // NB
    size_t o2 = (o1 + ((size_t)NB * 4) + 255) & ~(size_t)255;
    int* bbase = (int*)(ws + o2);                                      // NB+1
    size_t o3 = (o2 + ((size_t)(NB + 1) * 4) + 255) & ~(size_t)255;
    int* node_off = (int*)(ws + o3);                                   // N+1
    size_t o4 = (o3 + ((size_t)(N + 1) * 4) + 255) & ~(size_t)255;
    u64* bufA = (u64*)(ws + o4);                                       // E
    size_t o5 = (o4 + ((size_t)E * 8) + 255) & ~(size_t)255;
    u64* bufB = (u64*)(ws + o5);                                       // E
    size_t need = o5 + (size_t)E * 8;

    if (NB > NB_MAX || N > (1 << 20) || need > ws_size) {
        hipMemsetAsync(d_out, 0, (size_t)out_size * sizeof(float), stream);
        long long total = (long long)E * D_FEAT;
        int grid = (int)((total + 255) / 256);
        if (grid > 65536) grid = 65536;
        fallback_scatter<<<grid, 256, 0, stream>>>(edge_index, edge_attr, x, out, E);
        return;
    }

    const int epb = (E + NBLK - 1) / NBLK;

    binA_count<<<NBLK, ABLK, 0, stream>>>(edge_index, cnt, E, NB, epb);
    binS1<<<NB, NBLK, 0, stream>>>(cnt, btot, NB);
    binS2<<<1, NB_MAX, 0, stream>>>(btot, bbase, NB);
    binA_scatter<<<NBLK, ABLK, 0, stream>>>(edge_index, edge_attr, cnt, bbase, bufA, E, NB, epb);
    bucket_sort<<<NB, 256, 0, stream>>>(bufA, bufB, bbase, node_off, N, NB);

    const long long gthreads = (long long)N * 8;
    csr_gather<<<(int)((gthreads + 255) / 256), 256, 0, stream>>>(bufB, node_off, x, out, N);
}